// Round 4
// baseline (919.691 us; speedup 1.0000x reference)
//
#include <hip/hip_runtime.h>
#include <hip/hip_bf16.h>

#define BB 128
#define NN 512
#define CC 64
#define ALPHA_ 0.2f
#define NEG_INF_ -9.0e15f

__device__ __forceinline__ float bf2f(__hip_bfloat16 v) { return __bfloat162float(v); }

// k1: per row (b,n): h1 = x.W1 (bf16 -> ws), s1 = (h0+h1).a1, s2 = (h0+h1).a2.
// 4 waves/block, one row per wave. All inputs fp32.
__global__ __launch_bounds__(256) void k1_proj(
    const float* __restrict__ x, const float* __restrict__ W, const float* __restrict__ a,
    __hip_bfloat16* __restrict__ h1, float* __restrict__ s1, float* __restrict__ s2)
{
    __shared__ float sW0[4096];
    __shared__ float sW1[4096];
    __shared__ float sx[4][64];
    int tid = threadIdx.x;
    for (int idx = tid; idx < 4096; idx += 256) {
        sW0[idx] = W[idx];
        sW1[idx] = W[4096 + idx];
    }
    int wid = tid >> 6, lane = tid & 63;
    int row = blockIdx.x * 4 + wid;              // row = b*NN + n
    sx[wid][lane] = x[(size_t)row * 64 + lane];
    __syncthreads();

    float acc0 = 0.f, acc1 = 0.f;
    #pragma unroll
    for (int c = 0; c < 64; ++c) {
        float xv = sx[wid][c];
        acc0 = fmaf(xv, sW0[c * 64 + lane], acc0);
        acc1 = fmaf(xv, sW1[c * 64 + lane], acc1);
    }
    h1[(size_t)row * 64 + lane] = __float2bfloat16(acc1);

    float h = acc0 + acc1;
    float v1 = h * a[lane];
    float v2 = h * a[64 + lane];
    #pragma unroll
    for (int o = 32; o > 0; o >>= 1) {
        v1 += __shfl_xor(v1, o, 64);
        v2 += __shfl_xor(v2, o, 64);
    }
    if (lane == 0) { s1[row] = v1; s2[row] = v2; }
}

// k2: one block per (b, 4 rows i). Wave w owns row i = i0+w: scores, softmax.
// Phase C: block-wide sweep over j sharing each h1 load across the 4 rows.
__global__ __launch_bounds__(256) void k2_att(
    const int* __restrict__ adj,
    const float* __restrict__ x, const float* __restrict__ W, const float* __restrict__ bias,
    const __hip_bfloat16* __restrict__ h1,
    const float* __restrict__ s1, const float* __restrict__ s2,
    float* __restrict__ out)
{
    __shared__ float sW0[4096];                    // 16 KB, for h0-row recompute
    __shared__ float sxr[4][64];                   // x rows of the 4 i's
    __shared__ __align__(16) float sp[NN][4];      // transposed scores/probs [j][w]
    __shared__ float spart[4][4][64];              // [g][w][f]
    int tid = threadIdx.x, w = tid >> 6, lane = tid & 63;
    int b = blockIdx.y, i0 = blockIdx.x * 4;
    int i = i0 + w;

    for (int idx = tid; idx < 4096; idx += 256) sW0[idx] = W[idx];
    sxr[w][lane] = x[((size_t)b * NN + i) * 64 + lane];
    __syncthreads();

    // Phase A: masked leaky-relu scores for row i (one wave per row)
    const float* s2b = s2 + b * NN;
    float s1i = s1[b * NN + i];
    const int* adjr = adj + (size_t)i * NN;
    float lm = -3.4e38f;
    for (int j = lane; j < NN; j += 64) {
        float s = s1i + s2b[j];
        float e = s > 0.f ? s : ALPHA_ * s;
        if (adjr[j] <= 0) e = NEG_INF_;
        sp[j][w] = e;
        lm = fmaxf(lm, e);
    }
    #pragma unroll
    for (int o = 32; o > 0; o >>= 1) lm = fmaxf(lm, __shfl_xor(lm, o, 64));

    // Phase B: exponentiate, wave sum (same thread re-reads only its own j's)
    float ls = 0.f;
    for (int j = lane; j < NN; j += 64) {
        float p = __expf(sp[j][w] - lm);
        sp[j][w] = p;
        ls += p;
    }
    #pragma unroll
    for (int o = 32; o > 0; o >>= 1) ls += __shfl_xor(ls, o, 64);
    float inv = 1.f / ls;

    // h0[b,i,lane] recompute in fp32 (diag term)
    float h0f = 0.f;
    #pragma unroll
    for (int c = 0; c < 64; ++c) h0f = fmaf(sxr[w][c], sW0[c * 64 + lane], h0f);

    __syncthreads();  // all waves' probs visible

    // Phase C: tot[w'][f] = sum_j p[w'][j] * h1[b,j,f]; h1 load shared x4
    const __hip_bfloat16* h1b = h1 + (size_t)b * NN * 64;
    int g = w, f = lane;
    float a0 = 0.f, a1 = 0.f, a2 = 0.f, a3 = 0.f;
    for (int j = g; j < NN; j += 4) {
        float hv = bf2f(h1b[j * 64 + f]);
        float4 p4 = *(const float4*)&sp[j][0];     // 16B LDS broadcast
        a0 = fmaf(p4.x, hv, a0);
        a1 = fmaf(p4.y, hv, a1);
        a2 = fmaf(p4.z, hv, a2);
        a3 = fmaf(p4.w, hv, a3);
    }
    spart[g][0][f] = a0; spart[g][1][f] = a1; spart[g][2][f] = a2; spart[g][3][f] = a3;
    __syncthreads();

    float tot = spart[0][w][f] + spart[1][w][f] + spart[2][w][f] + spart[3][w][f];
    float pi  = sp[i][w];                          // p_i (included in tot; ref excludes diag)
    float hvi = bf2f(h1b[i * 64 + f]);
    float o = (tot - pi * hvi) * inv + (pi * inv) * h0f + bias[f];
    out[((size_t)b * NN + i) * 64 + f] = o;
}

extern "C" void kernel_launch(void* const* d_in, const int* in_sizes, int n_in,
                              void* d_out, int out_size, void* d_ws, size_t ws_size,
                              hipStream_t stream) {
    // Bind inputs by their (all-distinct) element counts, not by position.
    const void* p_x = nullptr; const void* p_adj = nullptr; const void* p_W = nullptr;
    const void* p_a = nullptr; const void* p_bias = nullptr;
    for (int k = 0; k < n_in; ++k) {
        switch (in_sizes[k]) {
            case 128 * 512 * 64: p_x    = d_in[k]; break;  // 4194304
            case 512 * 512:      p_adj  = d_in[k]; break;  // 262144
            case 2 * 64 * 64:    p_W    = d_in[k]; break;  // 8192
            case 2 * 64:         p_a    = d_in[k]; break;  // 128
            case 64:             p_bias = d_in[k]; break;  // 64
        }
    }
    const float* x    = (const float*)p_x;
    const int*   adj  = (const int*)p_adj;
    const float* W    = (const float*)p_W;
    const float* a    = (const float*)p_a;
    const float* bias = (const float*)p_bias;
    float* out = (float*)d_out;

    // Workspace (8.5 MB): h1 bf16 8 MB | s1 fp32 256 KB | s2 fp32 256 KB
    __hip_bfloat16* h1 = (__hip_bfloat16*)d_ws;
    float* s1 = (float*)(h1 + 4194304);
    float* s2 = s1 + 65536;

    k1_proj<<<dim3(BB * NN / 4), 256, 0, stream>>>(x, W, a, h1, s1, s2);
    k2_att<<<dim3(NN / 4, BB), 256, 0, stream>>>(adj, x, W, bias, h1, s1, s2, out);
}

// Round 5
// 249.156 us; speedup vs baseline: 3.6912x; 3.6912x over previous
//
#include <hip/hip_runtime.h>
#include <hip/hip_bf16.h>

#define BB 128
#define NN 512
#define ALPHA_ 0.2f
#define NEG_INF_ -9.0e15f
#define SPS 10   // prob-array row stride (floats): 8B-aligned pairs, 4-way bank conflict only

__device__ __forceinline__ float bf2f(__hip_bfloat16 v) { return __bfloat162float(v); }

__device__ __forceinline__ float rdlane(float v, int l) {
#if __has_builtin(__builtin_amdgcn_readlane)
    return __int_as_float(__builtin_amdgcn_readlane(__float_as_int(v), l));
#else
    return __shfl(v, l, 64);
#endif
}

// k1: h0 = x.W0, h1 = x.W1 (bf16 -> ws), s1/s2 row scores. No LDS: W cols in
// VGPRs (lane = f), x broadcast via readlane (VALU pipe, not LDS pipe).
#define K1_ROWS 16
__global__ __launch_bounds__(256) void k1_proj(
    const float* __restrict__ x, const float* __restrict__ W, const float* __restrict__ a,
    __hip_bfloat16* __restrict__ h1, __hip_bfloat16* __restrict__ h0,  // h0 may be null
    float* __restrict__ s1, float* __restrict__ s2)
{
    int lane = threadIdx.x & 63, w = threadIdx.x >> 6;
    float w0r[64], w1r[64];
    #pragma unroll
    for (int c = 0; c < 64; ++c) {
        w0r[c] = W[c * 64 + lane];
        w1r[c] = W[4096 + c * 64 + lane];
    }
    float a1v = a[lane], a2v = a[64 + lane];
    int base = (blockIdx.x * 4 + w) * K1_ROWS;
    for (int r = 0; r < K1_ROWS; ++r) {
        int row = base + r;
        float xv = x[(size_t)row * 64 + lane];
        float acc0 = 0.f, acc1 = 0.f;
        #pragma unroll
        for (int c = 0; c < 64; ++c) {
            float xs = rdlane(xv, c);
            acc0 = fmaf(xs, w0r[c], acc0);
            acc1 = fmaf(xs, w1r[c], acc1);
        }
        h1[(size_t)row * 64 + lane] = __float2bfloat16(acc1);
        if (h0) h0[(size_t)row * 64 + lane] = __float2bfloat16(acc0);
        float h = acc0 + acc1;
        float v1 = h * a1v, v2 = h * a2v;
        #pragma unroll
        for (int o = 32; o > 0; o >>= 1) {
            v1 += __shfl_xor(v1, o, 64);
            v2 += __shfl_xor(v2, o, 64);
        }
        if (lane == 0) { s1[row] = v1; s2[row] = v2; }
    }
}

// k2: one block per (b, 8 rows). 4 waves, 2 rows/wave for softmax; Phase C
// block-cooperative: each h1 element feeds 8 FMAs (one per row).
__global__ __launch_bounds__(256, 5) void k2_att(
    const int* __restrict__ adj,
    const float* __restrict__ x, const float* __restrict__ W, const float* __restrict__ bias,
    const __hip_bfloat16* __restrict__ h1,
    const __hip_bfloat16* __restrict__ h0,   // null => recompute diag row from x,W0
    const float* __restrict__ s1, const float* __restrict__ s2,
    float* __restrict__ out)
{
    __shared__ __align__(16) float spS[NN * SPS];   // 20 KB; later aliased as spart[4][8][64]
    int tid = threadIdx.x, w = tid >> 6, lane = tid & 63;
    int b = blockIdx.y, i0 = blockIdx.x * 8;

    // Phases A+B per row (wave w owns rows 2w, 2w+1)
    const float* s2b = s2 + b * NN;
    float inv[2], pi[2];
    for (int r2 = 0; r2 < 2; ++r2) {
        int r = 2 * w + r2;
        int i = i0 + r;
        float s1i = s1[b * NN + i];
        const int* adjr = adj + (size_t)i * NN;
        float lm = -3.4e38f;
        for (int j = lane; j < NN; j += 64) {
            float s = s1i + s2b[j];
            float e = s > 0.f ? s : ALPHA_ * s;
            if (adjr[j] <= 0) e = NEG_INF_;
            spS[j * SPS + r] = e;
            lm = fmaxf(lm, e);
        }
        #pragma unroll
        for (int o = 32; o > 0; o >>= 1) lm = fmaxf(lm, __shfl_xor(lm, o, 64));
        float ls = 0.f;
        for (int j = lane; j < NN; j += 64) {
            float p = __expf(spS[j * SPS + r] - lm);
            spS[j * SPS + r] = p;
            ls += p;
        }
        #pragma unroll
        for (int o = 32; o > 0; o >>= 1) ls += __shfl_xor(ls, o, 64);
        inv[r2] = 1.f / ls;
        pi[r2] = spS[i * SPS + r];   // own wave's write; wave-coherent
    }
    __syncthreads();   // all 8 rows' probs visible

    // Phase C: wave w handles j = w + 4k; 8 FMAs per h1 load
    const __hip_bfloat16* h1b = h1 + (size_t)b * NN * 64;
    const __hip_bfloat16* h1p = h1b + w * 64 + lane;
    float acc[8] = {0.f, 0.f, 0.f, 0.f, 0.f, 0.f, 0.f, 0.f};
    #pragma unroll 4
    for (int k = 0; k < 128; ++k) {
        int j = w + 4 * k;
        float hv = bf2f(h1p[k * 256]);
        const float* pr = &spS[j * SPS];
        float2 q0 = *(const float2*)(pr + 0);
        float2 q1 = *(const float2*)(pr + 2);
        float2 q2 = *(const float2*)(pr + 4);
        float2 q3 = *(const float2*)(pr + 6);
        acc[0] = fmaf(q0.x, hv, acc[0]);
        acc[1] = fmaf(q0.y, hv, acc[1]);
        acc[2] = fmaf(q1.x, hv, acc[2]);
        acc[3] = fmaf(q1.y, hv, acc[3]);
        acc[4] = fmaf(q2.x, hv, acc[4]);
        acc[5] = fmaf(q2.y, hv, acc[5]);
        acc[6] = fmaf(q3.x, hv, acc[6]);
        acc[7] = fmaf(q3.y, hv, acc[7]);
    }
    __syncthreads();   // everyone done reading probs; reuse spS as spart[4][8][64]
    #pragma unroll
    for (int r = 0; r < 8; ++r) spS[w * 512 + r * 64 + lane] = acc[r];
    __syncthreads();

    // Epilogue: wave w finishes rows 2w, 2w+1
    for (int r2 = 0; r2 < 2; ++r2) {
        int r = 2 * w + r2;
        int i = i0 + r;
        float tot = spS[0 * 512 + r * 64 + lane] + spS[1 * 512 + r * 64 + lane]
                  + spS[2 * 512 + r * 64 + lane] + spS[3 * 512 + r * 64 + lane];
        float hvi = bf2f(h1b[i * 64 + lane]);
        float h0v;
        if (h0) {
            h0v = bf2f(h0[((size_t)b * NN + i) * 64 + lane]);
        } else {
            float xv = x[((size_t)b * NN + i) * 64 + lane];
            float a0 = 0.f;
            #pragma unroll
            for (int c = 0; c < 64; ++c) a0 = fmaf(rdlane(xv, c), W[c * 64 + lane], a0);
            h0v = a0;
        }
        float o = (tot - pi[r2] * hvi) * inv[r2] + (pi[r2] * inv[r2]) * h0v + bias[lane];
        out[((size_t)b * NN + i) * 64 + lane] = o;
    }
}

extern "C" void kernel_launch(void* const* d_in, const int* in_sizes, int n_in,
                              void* d_out, int out_size, void* d_ws, size_t ws_size,
                              hipStream_t stream) {
    // Bind inputs by their (all-distinct) element counts.
    const void* p_x = nullptr; const void* p_adj = nullptr; const void* p_W = nullptr;
    const void* p_a = nullptr; const void* p_bias = nullptr;
    for (int k = 0; k < n_in; ++k) {
        switch (in_sizes[k]) {
            case 128 * 512 * 64: p_x    = d_in[k]; break;
            case 512 * 512:      p_adj  = d_in[k]; break;
            case 2 * 64 * 64:    p_W    = d_in[k]; break;
            case 2 * 64:         p_a    = d_in[k]; break;
            case 64:             p_bias = d_in[k]; break;
        }
    }
    const float* x    = (const float*)p_x;
    const int*   adj  = (const int*)p_adj;
    const float* W    = (const float*)p_W;
    const float* a    = (const float*)p_a;
    const float* bias = (const float*)p_bias;
    float* out = (float*)d_out;

    // ws: h1 bf16 8MB | s1 256KB | s2 256KB | (h0 bf16 8MB if room)
    __hip_bfloat16* h1 = (__hip_bfloat16*)d_ws;
    float* s1 = (float*)((char*)d_ws + (8u << 20));
    float* s2 = s1 + 65536;
    bool big = ws_size >= (size_t)(16.5 * 1024 * 1024);
    __hip_bfloat16* h0 = big ? (__hip_bfloat16*)((char*)d_ws + (8u << 20) + (512u << 10)) : nullptr;

    k1_proj<<<dim3(1024), 256, 0, stream>>>(x, W, a, h1, h0, s1, s2);
    k2_att<<<dim3(NN / 8, BB), 256, 0, stream>>>(adj, x, W, bias, h1, h0, s1, s2, out);
}

// Round 6
// 170.087 us; speedup vs baseline: 5.4072x; 1.4649x over previous
//
#include <hip/hip_runtime.h>
#include <hip/hip_bf16.h>

#define BB 128
#define NN 512
#define ALPHA_ 0.2f
#define NEG_INF_ -9.0e15f
#define SPB 520   // bf16 prob-row stride: 1040 B, 16B-aligned, banks spread (260 words ≡ 4 mod 32)

typedef short bf16x8 __attribute__((ext_vector_type(8)));   // 8 bf16 (4 VGPRs) — guide §3
typedef float f32x4  __attribute__((ext_vector_type(4)));

__device__ __forceinline__ float bf2f(__hip_bfloat16 v) { return __bfloat162float(v); }

__device__ __forceinline__ float rdlane(float v, int l) {
    return __int_as_float(__builtin_amdgcn_readlane(__float_as_int(v), l));
}

// k1: h0 = x.W0 -> d_out (fp32, row-major; k2 consumes then overwrites).
//     h1 = x.W1 -> ws transposed bf16: h1T[b][f][n]  (f-major so k2's MFMA
//     B-fragments are 16B-contiguous in k=j).
//     s1/s2 row scores. W held in VGPRs; x broadcast via readlane (no LDS pipe).
#define K1_ROWS 8
__global__ __launch_bounds__(256, 2) void k1_proj(
    const float* __restrict__ x, const float* __restrict__ W, const float* __restrict__ a,
    __hip_bfloat16* __restrict__ h1T, float* __restrict__ h0out,
    float* __restrict__ s1, float* __restrict__ s2)
{
    int lane = threadIdx.x & 63, w = threadIdx.x >> 6;
    float w0r[64], w1r[64];
    #pragma unroll
    for (int c = 0; c < 64; ++c) {
        w0r[c] = W[c * 64 + lane];
        w1r[c] = W[4096 + c * 64 + lane];
    }
    float a1v = a[lane], a2v = a[64 + lane];
    int base = (blockIdx.x * 4 + w) * K1_ROWS;
    for (int r = 0; r < K1_ROWS; ++r) {
        int row = base + r;                       // row = b*NN + n
        int b = row >> 9, n = row & 511;
        float xv = x[(size_t)row * 64 + lane];
        float acc0 = 0.f, acc1 = 0.f;
        #pragma unroll
        for (int c = 0; c < 64; ++c) {
            float xs = rdlane(xv, c);
            acc0 = fmaf(xs, w0r[c], acc0);
            acc1 = fmaf(xs, w1r[c], acc1);
        }
        h0out[(size_t)row * 64 + lane] = acc0;                          // coalesced fp32
        h1T[(size_t)b * 32768 + lane * 512 + n] = __float2bfloat16(acc1); // transposed scatter (L2 write-combines)
        float h = acc0 + acc1;
        float v1 = h * a1v, v2 = h * a2v;
        #pragma unroll
        for (int o = 32; o > 0; o >>= 1) {
            v1 += __shfl_xor(v1, o, 64);
            v2 += __shfl_xor(v2, o, 64);
        }
        if (lane == 0) { s1[row] = v1; s2[row] = v2; }
    }
}

// k2: block = (b, 16 rows i). Wave w: softmax for rows 4w..4w+3 -> bf16 probs in LDS;
// then MFMA O[16 x f-tile(16w)] = P(16x512) @ H1(512x64), B-frags direct from global h1T.
__global__ __launch_bounds__(256) void k2_att(
    const int* __restrict__ adj,
    const float* __restrict__ bias,
    const __hip_bfloat16* __restrict__ h1T,
    const float* __restrict__ s1, const float* __restrict__ s2,
    float* __restrict__ out)          // holds h0 on entry
{
    __shared__ __align__(16) __hip_bfloat16 sPb[16 * SPB];   // 16.6 KB
    __shared__ float sInv[16], sPi[16];
    int tid = threadIdx.x, w = tid >> 6, lane = tid & 63;
    int b = blockIdx.y, i0 = blockIdx.x * 16;
    const float* s2b = s2 + (size_t)b * NN;

    // Phases A+B: wave w owns rows r = 4w..4w+3
    for (int r2 = 0; r2 < 4; ++r2) {
        int r = 4 * w + r2;
        int i = i0 + r;
        float s1i = s1[(size_t)b * NN + i];
        const int* adjr = adj + (size_t)i * NN;
        float lm = -3.4e38f;
        #pragma unroll
        for (int t = 0; t < 8; ++t) {
            int j = lane + 64 * t;
            float s = s1i + s2b[j];
            float e = s > 0.f ? s : ALPHA_ * s;
            if (adjr[j] <= 0) e = NEG_INF_;
            lm = fmaxf(lm, e);
        }
        #pragma unroll
        for (int o = 32; o > 0; o >>= 1) lm = fmaxf(lm, __shfl_xor(lm, o, 64));
        float ls = 0.f;
        #pragma unroll
        for (int t = 0; t < 8; ++t) {
            int j = lane + 64 * t;
            float s = s1i + s2b[j];               // recompute (L1-hit) — no fp32 LDS round-trip
            float e = s > 0.f ? s : ALPHA_ * s;
            if (adjr[j] <= 0) e = NEG_INF_;
            float p = __expf(e - lm);
            ls += p;
            sPb[r * SPB + j] = __float2bfloat16(p);
            if (j == i) sPi[r] = p;
        }
        #pragma unroll
        for (int o = 32; o > 0; o >>= 1) ls += __shfl_xor(ls, o, 64);
        if (lane == 0) sInv[r] = 1.f / ls;
    }
    __syncthreads();

    // MFMA: A[m=lane&15][k=quad*8+t] from sPb; B[k=quad*8+t][n=lane&15] from h1T (n=f).
    int lane15 = lane & 15, quad = lane >> 4;
    int n0 = w * 16;
    const __hip_bfloat16* h1b = h1T + (size_t)b * 32768;
    const __hip_bfloat16* bptr = h1b + (size_t)(n0 + lane15) * 512 + quad * 8;
    const __hip_bfloat16* aptr = &sPb[lane15 * SPB + quad * 8];
    f32x4 acc = {0.f, 0.f, 0.f, 0.f};
    #pragma unroll
    for (int kt = 0; kt < 16; ++kt) {
        bf16x8 af = *(const bf16x8*)(aptr + kt * 32);
        bf16x8 bf = *(const bf16x8*)(bptr + kt * 32);
        acc = __builtin_amdgcn_mfma_f32_16x16x32_bf16(af, bf, acc, 0, 0, 0);
    }

    // Epilogue: D[m=quad*4+r][f=n0+lane15]; subtract diag p_i*h1[i][f], add p_i*inv*h0 + bias.
    int f = n0 + lane15;
    float biasf = bias[f];
    #pragma unroll
    for (int r = 0; r < 4; ++r) {
        int m = quad * 4 + r;
        int i = i0 + m;
        size_t oidx = ((size_t)b * NN + i) * 64 + f;
        float hvi = bf2f(h1b[(size_t)f * 512 + i]);
        float h0v = out[oidx];                    // h0 written by k1
        float pi = sPi[m], inv = sInv[m];
        float o = (acc[r] - pi * hvi) * inv + pi * inv * h0v + biasf;
        out[oidx] = o;
    }
}

extern "C" void kernel_launch(void* const* d_in, const int* in_sizes, int n_in,
                              void* d_out, int out_size, void* d_ws, size_t ws_size,
                              hipStream_t stream) {
    // Bind inputs by their (all-distinct) element counts.
    const void* p_x = nullptr; const void* p_adj = nullptr; const void* p_W = nullptr;
    const void* p_a = nullptr; const void* p_bias = nullptr;
    for (int k = 0; k < n_in; ++k) {
        switch (in_sizes[k]) {
            case 128 * 512 * 64: p_x    = d_in[k]; break;
            case 512 * 512:      p_adj  = d_in[k]; break;
            case 2 * 64 * 64:    p_W    = d_in[k]; break;
            case 2 * 64:         p_a    = d_in[k]; break;
            case 64:             p_bias = d_in[k]; break;
        }
    }
    const float* x    = (const float*)p_x;
    const int*   adj  = (const int*)p_adj;
    const float* W    = (const float*)p_W;
    const float* a    = (const float*)p_a;
    const float* bias = (const float*)p_bias;
    float* out = (float*)d_out;

    // ws (8.5 MB): h1T bf16 8 MB | s1 fp32 256 KB | s2 fp32 256 KB
    __hip_bfloat16* h1T = (__hip_bfloat16*)d_ws;
    float* s1 = (float*)((char*)d_ws + (8u << 20));
    float* s2 = s1 + 65536;

    k1_proj<<<dim3(BB * NN / (4 * K1_ROWS)), 256, 0, stream>>>(x, W, a, h1T, out, s1, s2);
    k2_att<<<dim3(NN / 16, BB), 256, 0, stream>>>(adj, bias, h1T, s1, s2, out);
}

// Round 7
// 154.862 us; speedup vs baseline: 5.9388x; 1.0983x over previous
//
#include <hip/hip_runtime.h>
#include <hip/hip_bf16.h>

#define BB 128
#define NN 512
#define ALPHA_ 0.2f
#define NEG_INF_ -9.0e15f
#define SPB 536   // bf16 prob-row stride: 1072 B (16B-aligned); 268 dwords ≡ 12 mod 32 → ~2-way only

typedef short bf16x8 __attribute__((ext_vector_type(8)));
typedef float f32x4  __attribute__((ext_vector_type(4)));

__device__ __forceinline__ float bf2f(__hip_bfloat16 v) { return __bfloat162float(v); }

__device__ __forceinline__ float rdlane(float v, int l) {
    return __int_as_float(__builtin_amdgcn_readlane(__float_as_int(v), l));
}

// k0: pack adj (int32 0/1) into bitmask: bits[i*64 + by] bit t = adj[i][8*by+t] > 0
__global__ __launch_bounds__(256) void k0_bits(const int* __restrict__ adj,
                                               unsigned char* __restrict__ bits) {
    int idx = blockIdx.x * 256 + threadIdx.x;     // 0..32767
    const int* p = adj + (size_t)idx * 8;
    unsigned m = 0;
    #pragma unroll
    for (int t = 0; t < 8; ++t) m |= (p[t] > 0 ? 1u : 0u) << t;
    bits[idx] = (unsigned char)m;
}

// k1: block = (b, 64-row n-tile). h0 = x.W0 -> d_out fp32 (k2 consumes then overwrites).
// h1 -> LDS transpose -> h1T[b][f][n] bf16 with 128B-contiguous stores. s1/s2 row scores.
__global__ __launch_bounds__(256, 2) void k1_proj(
    const float* __restrict__ x, const float* __restrict__ W, const float* __restrict__ a,
    __hip_bfloat16* __restrict__ h1T, float* __restrict__ h0out,
    float* __restrict__ s1, float* __restrict__ s2)
{
    __shared__ unsigned short sT[64 * 66];        // [f][n_local], stride 66 halfwords (33 dw ≡ 1 mod 32)
    int lane = threadIdx.x & 63, w = threadIdx.x >> 6;
    int b = blockIdx.x >> 3, n0 = (blockIdx.x & 7) << 6;

    float w0r[64], w1r[64];
    #pragma unroll
    for (int c = 0; c < 64; ++c) {
        w0r[c] = W[c * 64 + lane];
        w1r[c] = W[4096 + c * 64 + lane];
    }
    float a1v = a[lane], a2v = a[64 + lane];

    for (int r = 0; r < 16; ++r) {
        int nl = w * 16 + r;
        int row = b * NN + n0 + nl;
        float xv = x[(size_t)row * 64 + lane];
        float acc0 = 0.f, acc1 = 0.f;
        #pragma unroll
        for (int c = 0; c < 64; ++c) {
            float xs = rdlane(xv, c);
            acc0 = fmaf(xs, w0r[c], acc0);
            acc1 = fmaf(xs, w1r[c], acc1);
        }
        h0out[(size_t)row * 64 + lane] = acc0;    // coalesced fp32
        __hip_bfloat16 hb = __float2bfloat16(acc1);
        sT[lane * 66 + nl] = *(unsigned short*)&hb;  // conflict-free (stride 33 dw)
        float h = acc0 + acc1;
        float v1 = h * a1v, v2 = h * a2v;
        #pragma unroll
        for (int o = 32; o > 0; o >>= 1) {
            v1 += __shfl_xor(v1, o, 64);
            v2 += __shfl_xor(v2, o, 64);
        }
        if (lane == 0) { s1[row] = v1; s2[row] = v2; }
    }
    __syncthreads();
    // write h1T: wave w writes f-rows w*16..w*16+15, 128B contiguous per row
    unsigned short* h1Tu = (unsigned short*)h1T;
    for (int fr = 0; fr < 16; ++fr) {
        int f = w * 16 + fr;
        h1Tu[(size_t)b * 32768 + f * 512 + n0 + lane] = sT[f * 66 + lane];
    }
}

// k2: block = (b, 16 rows i). Wave w: single-pass softmax for rows 4w..4w+3 (lane owns
// 8 contiguous j; s2 reg-cached; adj via bitmask); probs bf16 in LDS; MFMA P@H1 with
// B-frags direct from global h1T; epilogue fixes diag + bias in-place over h0 (in d_out).
__global__ __launch_bounds__(256) void k2_att(
    const unsigned char* __restrict__ adjbits,
    const float* __restrict__ bias,
    const __hip_bfloat16* __restrict__ h1T,
    const float* __restrict__ s1, const float* __restrict__ s2,
    float* __restrict__ out)          // holds h0 on entry
{
    __shared__ __align__(16) __hip_bfloat16 sPb[16 * SPB];   // 16.75 KB
    __shared__ float sInv[16];
    int tid = threadIdx.x, w = tid >> 6, lane = tid & 63;
    int b = blockIdx.y, i0 = blockIdx.x * 16;

    // s2 for this b: lane caches its 8 contiguous j's once (reused all 4 rows)
    const float* s2b = s2 + (size_t)b * NN;
    float4 q0 = *(const float4*)(s2b + lane * 8);
    float4 q1 = *(const float4*)(s2b + lane * 8 + 4);
    float sv[8] = {q0.x, q0.y, q0.z, q0.w, q1.x, q1.y, q1.z, q1.w};

    for (int r2 = 0; r2 < 4; ++r2) {
        int r = 4 * w + r2;
        int i = i0 + r;
        float s1i = s1[(size_t)b * NN + i];
        unsigned mb = adjbits[(size_t)i * 64 + lane];
        float e[8];
        #pragma unroll
        for (int t = 0; t < 8; ++t) {
            float s = s1i + sv[t];
            s = fmaxf(s, ALPHA_ * s);             // leaky-relu (alpha<1)
            e[t] = (mb & (1u << t)) ? s : NEG_INF_;
        }
        float lm = fmaxf(fmaxf(fmaxf(e[0], e[1]), fmaxf(e[2], e[3])),
                         fmaxf(fmaxf(e[4], e[5]), fmaxf(e[6], e[7])));
        #pragma unroll
        for (int o = 32; o > 0; o >>= 1) lm = fmaxf(lm, __shfl_xor(lm, o, 64));
        float p[8], ls = 0.f;
        #pragma unroll
        for (int t = 0; t < 8; ++t) { p[t] = __expf(e[t] - lm); ls += p[t]; }
        #pragma unroll
        for (int o = 32; o > 0; o >>= 1) ls += __shfl_xor(ls, o, 64);
        if (lane == 0) sInv[r] = 1.f / ls;
        union { bf16x8 v; __hip_bfloat16 h[8]; } pk;
        #pragma unroll
        for (int t = 0; t < 8; ++t) pk.h[t] = __float2bfloat16(p[t]);
        *(bf16x8*)&sPb[r * SPB + lane * 8] = pk.v;   // one ds_write_b128
    }
    __syncthreads();

    // MFMA: A[m=lane&15][k=quad*8+t] from sPb; B[k][n=lane&15] from h1T (n=f)
    int lane15 = lane & 15, quad = lane >> 4;
    int n0w = w * 16;
    const __hip_bfloat16* h1b = h1T + (size_t)b * 32768;
    const __hip_bfloat16* bptr = h1b + (size_t)(n0w + lane15) * 512 + quad * 8;
    const __hip_bfloat16* aptr = &sPb[lane15 * SPB + quad * 8];
    f32x4 acc = {0.f, 0.f, 0.f, 0.f};
    #pragma unroll
    for (int kt = 0; kt < 16; ++kt) {
        bf16x8 af = *(const bf16x8*)(aptr + kt * 32);
        bf16x8 bf = *(const bf16x8*)(bptr + kt * 32);
        acc = __builtin_amdgcn_mfma_f32_16x16x32_bf16(af, bf, acc, 0, 0, 0);
    }

    // Epilogue: D[m=quad*4+r][f]; remove diag p_i*h1[i][f], add p_i*inv*h0 + bias
    int f = n0w + lane15;
    float biasf = bias[f];
    #pragma unroll
    for (int r = 0; r < 4; ++r) {
        int m = quad * 4 + r;
        int i = i0 + m;
        size_t oidx = ((size_t)b * NN + i) * 64 + f;
        float hvi = bf2f(h1b[(size_t)f * 512 + i]);
        float pi  = bf2f(sPb[m * SPB + i]);       // same bf16 value the MFMA consumed
        float h0v = out[oidx];
        float inv = sInv[m];
        out[oidx] = (acc[r] - pi * hvi) * inv + pi * inv * h0v + biasf;
    }
}

extern "C" void kernel_launch(void* const* d_in, const int* in_sizes, int n_in,
                              void* d_out, int out_size, void* d_ws, size_t ws_size,
                              hipStream_t stream) {
    // Bind inputs by their (all-distinct) element counts.
    const void* p_x = nullptr; const void* p_adj = nullptr; const void* p_W = nullptr;
    const void* p_a = nullptr; const void* p_bias = nullptr;
    for (int k = 0; k < n_in; ++k) {
        switch (in_sizes[k]) {
            case 128 * 512 * 64: p_x    = d_in[k]; break;
            case 512 * 512:      p_adj  = d_in[k]; break;
            case 2 * 64 * 64:    p_W    = d_in[k]; break;
            case 2 * 64:         p_a    = d_in[k]; break;
            case 64:             p_bias = d_in[k]; break;
        }
    }
    const float* x    = (const float*)p_x;
    const int*   adj  = (const int*)p_adj;
    const float* W    = (const float*)p_W;
    const float* a    = (const float*)p_a;
    const float* bias = (const float*)p_bias;
    float* out = (float*)d_out;

    // ws (8.8 MB): h1T bf16 8MB | s1 256KB | s2 256KB | adjbits 32KB
    __hip_bfloat16* h1T = (__hip_bfloat16*)d_ws;
    float* s1 = (float*)((char*)d_ws + (8u << 20));
    float* s2 = s1 + 65536;
    unsigned char* adjbits = (unsigned char*)(s2 + 65536);

    k0_bits<<<dim3(128), 256, 0, stream>>>(adj, adjbits);
    k1_proj<<<dim3(BB * 8), 256, 0, stream>>>(x, W, a, h1T, out, s1, s2);
    k2_att<<<dim3(NN / 16, BB), 256, 0, stream>>>(adjbits, bias, h1T, s1, s2, out);
}

// Round 8
// 117.161 us; speedup vs baseline: 7.8498x; 1.3218x over previous
//
#include <hip/hip_runtime.h>
#include <hip/hip_bf16.h>

#define BB 128
#define NN 512
#define ALPHA_ 0.2f
#define NEG_INF_ -9.0e15f
#define SPB 536   // bf16 prob-row stride (hw): 67 16B-granules ≡ 3 mod 8 → spread, ~2-way max
#define SXW 72    // A/B fragment LDS stride (hw): 9 granules ≡ 1 mod 8 → spread

typedef short bf16x8 __attribute__((ext_vector_type(8)));
typedef float f32x4  __attribute__((ext_vector_type(4)));

__device__ __forceinline__ float bf2f(__hip_bfloat16 v) { return __bfloat162float(v); }

// k0: pack adj (int32 0/1) into bitmask: bits[i*64 + by] bit t = adj[i][8*by+t] > 0
__global__ __launch_bounds__(256) void k0_bits(const int* __restrict__ adj,
                                               unsigned char* __restrict__ bits) {
    int idx = blockIdx.x * 256 + threadIdx.x;     // 0..32767
    const int* p = adj + (size_t)idx * 8;
    unsigned m = 0;
    #pragma unroll
    for (int t = 0; t < 8; ++t) m |= (p[t] > 0 ? 1u : 0u) << t;
    bits[idx] = (unsigned char)m;
}

// k1 (MFMA): block = (b, 64-node tile). h0 = x.W0 -> d_out fp32; h1 -> LDS transpose
// -> h1T[b][f][n] bf16 (128B-contiguous stores); s1/s2 from fp32 accumulators.
__global__ __launch_bounds__(256, 2) void k1_proj(
    const float* __restrict__ x, const float* __restrict__ W, const float* __restrict__ a,
    __hip_bfloat16* __restrict__ h1T, float* __restrict__ h0out,
    float* __restrict__ s1, float* __restrict__ s2)
{
    __shared__ __align__(16) unsigned short sX[64 * SXW];       // x tile, A-layout [n_local][c]
    __shared__ __align__(16) unsigned short sWb[2][64 * SXW];   // W^T, B-layout [f][c]
    __shared__ unsigned short sT[64 * 66];                      // h1 transpose [f][n_local]
    int tid = threadIdx.x, lane = tid & 63, w = tid >> 6;
    int lane15 = lane & 15, quad = lane >> 4;
    int b = blockIdx.x >> 3, n0 = (blockIdx.x & 7) << 6;

    // stage W transposed to bf16 B-layout
    for (int idx = tid; idx < 4096; idx += 256) {
        int c = idx >> 6, f = idx & 63;
        __hip_bfloat16 b0 = __float2bfloat16(W[idx]);
        __hip_bfloat16 b1 = __float2bfloat16(W[4096 + idx]);
        sWb[0][f * SXW + c] = *(unsigned short*)&b0;
        sWb[1][f * SXW + c] = *(unsigned short*)&b1;
    }
    // stage x tile to bf16 A-layout: thread = (row nl = tid>>2, quarter q = tid&3)
    {
        int nl = tid >> 2, q = tid & 3;
        const float* xp = x + ((size_t)b * NN + n0 + nl) * 64 + q * 16;
        float4 v0 = *(const float4*)(xp + 0);
        float4 v1 = *(const float4*)(xp + 4);
        float4 v2 = *(const float4*)(xp + 8);
        float4 v3 = *(const float4*)(xp + 12);
        union { bf16x8 v; __hip_bfloat16 h[8]; } pk0, pk1;
        pk0.h[0]=__float2bfloat16(v0.x); pk0.h[1]=__float2bfloat16(v0.y);
        pk0.h[2]=__float2bfloat16(v0.z); pk0.h[3]=__float2bfloat16(v0.w);
        pk0.h[4]=__float2bfloat16(v1.x); pk0.h[5]=__float2bfloat16(v1.y);
        pk0.h[6]=__float2bfloat16(v1.z); pk0.h[7]=__float2bfloat16(v1.w);
        pk1.h[0]=__float2bfloat16(v2.x); pk1.h[1]=__float2bfloat16(v2.y);
        pk1.h[2]=__float2bfloat16(v2.z); pk1.h[3]=__float2bfloat16(v2.w);
        pk1.h[4]=__float2bfloat16(v3.x); pk1.h[5]=__float2bfloat16(v3.y);
        pk1.h[6]=__float2bfloat16(v3.z); pk1.h[7]=__float2bfloat16(v3.w);
        *(bf16x8*)&sX[nl * SXW + q * 16]     = pk0.v;
        *(bf16x8*)&sX[nl * SXW + q * 16 + 8] = pk1.v;
    }
    __syncthreads();

    // MFMA: wave w owns m-stripe rows w*16..w*16+15; 4 n-tiles x 2 mats, K=64 (2 steps)
    f32x4 acc0[4] = {{0,0,0,0},{0,0,0,0},{0,0,0,0},{0,0,0,0}};
    f32x4 acc1[4] = {{0,0,0,0},{0,0,0,0},{0,0,0,0},{0,0,0,0}};
    #pragma unroll
    for (int kt = 0; kt < 2; ++kt) {
        bf16x8 af = *(const bf16x8*)&sX[(w * 16 + lane15) * SXW + kt * 32 + quad * 8];
        #pragma unroll
        for (int nt = 0; nt < 4; ++nt) {
            bf16x8 b0 = *(const bf16x8*)&sWb[0][(nt * 16 + lane15) * SXW + kt * 32 + quad * 8];
            acc0[nt] = __builtin_amdgcn_mfma_f32_16x16x32_bf16(af, b0, acc0[nt], 0, 0, 0);
            bf16x8 b1 = *(const bf16x8*)&sWb[1][(nt * 16 + lane15) * SXW + kt * 32 + quad * 8];
            acc1[nt] = __builtin_amdgcn_mfma_f32_16x16x32_bf16(af, b1, acc1[nt], 0, 0, 0);
        }
    }

    // epilogue: D[m = quad*4+r][f = nt*16+lane15], m-stripe base w*16
    float a1v[4], a2v[4];
    #pragma unroll
    for (int nt = 0; nt < 4; ++nt) {
        a1v[nt] = a[nt * 16 + lane15];
        a2v[nt] = a[64 + nt * 16 + lane15];
    }
    float p1[4] = {0, 0, 0, 0}, p2[4] = {0, 0, 0, 0};
    #pragma unroll
    for (int nt = 0; nt < 4; ++nt) {
        #pragma unroll
        for (int r = 0; r < 4; ++r) {
            int nl = w * 16 + quad * 4 + r;
            int f  = nt * 16 + lane15;
            float h0v = acc0[nt][r], h1v = acc1[nt][r];
            h0out[((size_t)b * NN + n0 + nl) * 64 + f] = h0v;
            __hip_bfloat16 hb = __float2bfloat16(h1v);
            sT[f * 66 + nl] = *(unsigned short*)&hb;
            float hs = h0v + h1v;
            p1[r] = fmaf(hs, a1v[nt], p1[r]);
            p2[r] = fmaf(hs, a2v[nt], p2[r]);
        }
    }
    #pragma unroll
    for (int r = 0; r < 4; ++r) {
        float v1 = p1[r], v2 = p2[r];
        #pragma unroll
        for (int o = 1; o < 16; o <<= 1) {
            v1 += __shfl_xor(v1, o, 64);
            v2 += __shfl_xor(v2, o, 64);
        }
        if (lane15 == 0) {
            int row = b * NN + n0 + w * 16 + quad * 4 + r;
            s1[row] = v1; s2[row] = v2;
        }
    }
    __syncthreads();
    // h1T: wave w writes f-rows w*16..w*16+15, 128B contiguous
    unsigned short* h1Tu = (unsigned short*)h1T;
    #pragma unroll
    for (int fr = 0; fr < 16; ++fr) {
        int f = w * 16 + fr;
        h1Tu[(size_t)b * 32768 + f * 512 + n0 + lane] = sT[f * 66 + lane];
    }
}

// k2: block = (b, 32 rows). Wave w: softmax rows 8w..8w+7 (bitmask adj, reg-cached s2);
// MFMA with explicit 8-deep B-frag register prefetch; B shared across 2 m-tiles.
__global__ __launch_bounds__(256, 2) void k2_att(
    const unsigned char* __restrict__ adjbits,
    const float* __restrict__ bias,
    const __hip_bfloat16* __restrict__ h1T,
    const float* __restrict__ s1, const float* __restrict__ s2,
    float* __restrict__ out)          // holds h0 on entry
{
    __shared__ __align__(16) __hip_bfloat16 sPb[32 * SPB];   // 34.3 KB
    __shared__ float sInv[32];
    int tid = threadIdx.x, w = tid >> 6, lane = tid & 63;
    int b = blockIdx.y, i0 = blockIdx.x * 32;

    const float* s2b = s2 + (size_t)b * NN;
    float4 q0 = *(const float4*)(s2b + lane * 8);
    float4 q1 = *(const float4*)(s2b + lane * 8 + 4);
    float sv[8] = {q0.x, q0.y, q0.z, q0.w, q1.x, q1.y, q1.z, q1.w};

    for (int r2 = 0; r2 < 8; ++r2) {
        int r = 8 * w + r2;
        int i = i0 + r;
        float s1i = s1[(size_t)b * NN + i];
        unsigned mb = adjbits[(size_t)i * 64 + lane];
        float e[8];
        #pragma unroll
        for (int t = 0; t < 8; ++t) {
            float s = s1i + sv[t];
            s = fmaxf(s, ALPHA_ * s);
            e[t] = (mb & (1u << t)) ? s : NEG_INF_;
        }
        float lm = fmaxf(fmaxf(fmaxf(e[0], e[1]), fmaxf(e[2], e[3])),
                         fmaxf(fmaxf(e[4], e[5]), fmaxf(e[6], e[7])));
        #pragma unroll
        for (int o = 32; o > 0; o >>= 1) lm = fmaxf(lm, __shfl_xor(lm, o, 64));
        float p[8], ls = 0.f;
        #pragma unroll
        for (int t = 0; t < 8; ++t) { p[t] = __expf(e[t] - lm); ls += p[t]; }
        #pragma unroll
        for (int o = 32; o > 0; o >>= 1) ls += __shfl_xor(ls, o, 64);
        if (lane == 0) sInv[r] = 1.f / ls;
        union { bf16x8 v; __hip_bfloat16 h[8]; } pk;
        #pragma unroll
        for (int t = 0; t < 8; ++t) pk.h[t] = __float2bfloat16(p[t]);
        *(bf16x8*)&sPb[r * SPB + lane * 8] = pk.v;
    }
    __syncthreads();

    // MFMA: wave w = f-tile n0w; two m-tiles (rows 0..15, 16..31) share B-frags
    int lane15 = lane & 15, quad = lane >> 4;
    int n0w = w * 16;
    const __hip_bfloat16* h1b = h1T + (size_t)b * 32768;
    const __hip_bfloat16* bptr = h1b + (size_t)(n0w + lane15) * 512 + quad * 8;
    const __hip_bfloat16* aptr0 = &sPb[lane15 * SPB + quad * 8];
    const __hip_bfloat16* aptr1 = &sPb[(16 + lane15) * SPB + quad * 8];
    f32x4 acc0 = {0, 0, 0, 0}, acc1 = {0, 0, 0, 0};
    bf16x8 bfr[8];
    #pragma unroll
    for (int half = 0; half < 2; ++half) {
        #pragma unroll
        for (int g = 0; g < 8; ++g)
            bfr[g] = *(const bf16x8*)(bptr + (half * 8 + g) * 32);
        #pragma unroll
        for (int g = 0; g < 8; ++g) {
            int kt = half * 8 + g;
            bf16x8 a0 = *(const bf16x8*)(aptr0 + kt * 32);
            acc0 = __builtin_amdgcn_mfma_f32_16x16x32_bf16(a0, bfr[g], acc0, 0, 0, 0);
            bf16x8 a1 = *(const bf16x8*)(aptr1 + kt * 32);
            acc1 = __builtin_amdgcn_mfma_f32_16x16x32_bf16(a1, bfr[g], acc1, 0, 0, 0);
        }
    }

    // Epilogue: D[m=quad*4+r][f]; remove diag, add p_i*inv*h0 + bias
    int f = n0w + lane15;
    float biasf = bias[f];
    #pragma unroll
    for (int t = 0; t < 2; ++t) {
        f32x4 ac = t ? acc1 : acc0;
        #pragma unroll
        for (int r = 0; r < 4; ++r) {
            int m = t * 16 + quad * 4 + r;
            int i = i0 + m;
            size_t oidx = ((size_t)b * NN + i) * 64 + f;
            float hvi = bf2f(h1b[(size_t)f * 512 + i]);
            float pi  = bf2f(sPb[m * SPB + i]);
            float h0v = out[oidx];
            float inv = sInv[m];
            out[oidx] = (ac[r] - pi * hvi) * inv + pi * inv * h0v + biasf;
        }
    }
}

extern "C" void kernel_launch(void* const* d_in, const int* in_sizes, int n_in,
                              void* d_out, int out_size, void* d_ws, size_t ws_size,
                              hipStream_t stream) {
    const void* p_x = nullptr; const void* p_adj = nullptr; const void* p_W = nullptr;
    const void* p_a = nullptr; const void* p_bias = nullptr;
    for (int k = 0; k < n_in; ++k) {
        switch (in_sizes[k]) {
            case 128 * 512 * 64: p_x    = d_in[k]; break;
            case 512 * 512:      p_adj  = d_in[k]; break;
            case 2 * 64 * 64:    p_W    = d_in[k]; break;
            case 2 * 64:         p_a    = d_in[k]; break;
            case 64:             p_bias = d_in[k]; break;
        }
    }
    const float* x    = (const float*)p_x;
    const int*   adj  = (const int*)p_adj;
    const float* W    = (const float*)p_W;
    const float* a    = (const float*)p_a;
    const float* bias = (const float*)p_bias;
    float* out = (float*)d_out;

    // ws (8.8 MB): h1T bf16 8MB | s1 256KB | s2 256KB | adjbits 32KB
    __hip_bfloat16* h1T = (__hip_bfloat16*)d_ws;
    float* s1 = (float*)((char*)d_ws + (8u << 20));
    float* s2 = s1 + 65536;
    unsigned char* adjbits = (unsigned char*)(s2 + 65536);

    k0_bits<<<dim3(128), 256, 0, stream>>>(adj, adjbits);
    k1_proj<<<dim3(BB * 8), 256, 0, stream>>>(x, W, a, h1T, out, s1, s2);
    k2_att<<<dim3(NN / 32, BB), 256, 0, stream>>>(adjbits, bias, h1T, s1, s2, out);
}